// Round 10
// baseline (191.385 us; speedup 1.0000x reference)
//
#include <hip/hip_runtime.h>
#include <hip/hip_bf16.h>
#include <math.h>

#define NB 16
#define NT 2048
#define ND 512
#define NH 64

typedef __attribute__((ext_vector_type(8))) short short8;
typedef __attribute__((ext_vector_type(4))) float float4v;

__device__ __forceinline__ bool mask_is_bytes(const int* m) {
    return m[0] == 0x01010101;
}
__device__ __forceinline__ bool mask_at(const int* m, bool bytes, int i) {
    if (bytes) return ((const unsigned char*)m)[i] != 0;
    return m[i] != 0;
}

// Minkowski dot, metric folded into `a`; explicit fmaf so pass 1 / pass 2
// recompute bitwise-identical values.
__device__ __forceinline__ float dot4(float4 a, float4 p) {
    float d = a.x * p.x;
    d = __builtin_fmaf(a.y, p.y, d);
    d = __builtin_fmaf(a.z, p.z, d);
    d = __builtin_fmaf(a.w, p.w, d);
    return d;
}

__device__ __forceinline__ unsigned short f2bf(float x) {
    unsigned int u = __float_as_uint(x);
    u += 0x7fffu + ((u >> 16) & 1u);
    return (unsigned short)(u >> 16);
}

// 8-slot sorted-descending insert via med3 chain. Exact no-op when D < V7.
#define INS8(V0,V1,V2,V3,V4,V5,V6,V7,D)                          \
    {                                                            \
        float n0 = fmaxf(V0, D);                                 \
        float n1 = __builtin_amdgcn_fmed3f(D, V0, V1);           \
        float n2 = __builtin_amdgcn_fmed3f(D, V1, V2);           \
        float n3 = __builtin_amdgcn_fmed3f(D, V2, V3);           \
        float n4 = __builtin_amdgcn_fmed3f(D, V3, V4);           \
        float n5 = __builtin_amdgcn_fmed3f(D, V4, V5);           \
        float n6 = __builtin_amdgcn_fmed3f(D, V5, V6);           \
        float n7 = __builtin_amdgcn_fmed3f(D, V6, V7);           \
        V0 = n0; V1 = n1; V2 = n2; V3 = n3;                      \
        V4 = n4; V5 = n5; V6 = n6; V7 = n7;                      \
    }

// ---------------------------------------------------------------------------
// Kernel A: one-time W2 fp32[k][n] -> bf16 W2t[n][k].
// ---------------------------------------------------------------------------
__global__ void __launch_bounds__(256) w2t_kernel(
        const float* __restrict__ W2, unsigned short* __restrict__ W2t) {
    int i = blockIdx.x * 256 + threadIdx.x;
    int n = i & (ND - 1), k = i >> 9;
    W2t[n * NH + k] = f2bf(W2[k * ND + n]);
}

// ---------------------------------------------------------------------------
// Kernel B: fused. 1024 thr = 16 waves, block owns 128 tokens (2/lane).
// Grid 256 = 1 block/CU but 16 waves/CU (R8's TLP) with R9's halved LDS
// traffic (each broadcast ps read feeds 2 dots; chunk C = L/16).
// scratch union 64 KB: vtop [16][8][128]; psum two-stage into [8][12][128].
// Pass-1 wave-skip ballot: INS8 is a bit-exact no-op when d < v7, so
// skipping when no lane inserts preserves exact semantics.
// ---------------------------------------------------------------------------
#define VT(w2, j, l)  scratch[((w2) * 8 + (j)) * 128 + (l)]   // w2 0..15
#define PS(w2, c, l)  scratch[((w2) * 12 + (c)) * 128 + (l)]  // w2 0..7

__global__ void __launch_bounds__(1024, 4) fused_topk_mass_mlp_kernel(
        const float* __restrict__ tok,
        const int* __restrict__ mask,
        const float* __restrict__ W1,
        const float* __restrict__ b1,
        const unsigned short* __restrict__ W2t,
        const float* __restrict__ b2,
        float* __restrict__ out) {
    __shared__ float Plds[NT * 4];            // 32 KB
    __shared__ float scratch[16 * 8 * 128];   // 64 KB (vtop; psum reuses)
    __shared__ unsigned short hs[128][88];    // 22.5 KB
    __shared__ float mass_s[3][128];          // 1.5 KB
    __shared__ int wcnt[16];

    const int b    = blockIdx.y;
    const int t0   = blockIdx.x * 128;
    const int tid  = threadIdx.x;
    const int lane = tid & 63;
    const int w    = tid >> 6;                // 0..15
    const bool mb  = mask_is_bytes(mask);

    const bool blockValid = mask_at(mask, mb, b * NT + t0);   // mask monotone

    if (blockValid) {
        // ---- stage tokens -> P in LDS; count L ----
        int cnt = 0;
#pragma unroll
        for (int it = 0; it < 2; ++it) {
            int i = tid + it * 1024;
            float4 tv = ((const float4*)tok)[b * NT + i];
            bool m = mask_at(mask, mb, b * NT + i);
            float E = tv.x, Pt = tv.y, eta = tv.z, phi = tv.w;
            float px = Pt * cosf(phi);
            float py = Pt * sinf(phi);
            float pz = Pt * sinhf(fminf(fmaxf(eta, -20.f), 20.f));
            float4 pv = m ? make_float4(E, px, py, pz)
                          : make_float4(-1e30f, 0.f, 0.f, 0.f);
            *(float4*)&Plds[i * 4] = pv;
            cnt += (int)__popcll(__ballot(m));
        }
        if (lane == 0) wcnt[w] = cnt;
        __syncthreads();                               // B1

        int L = 0;
#pragma unroll
        for (int j = 0; j < 16; ++j) L += wcnt[j];
        const int C    = (L + 15) >> 4;
        const int sBeg = w * C;
        const int sEnd = min(sBeg + C, L);

        float4 ptA = *(const float4*)&Plds[(t0 + lane) * 4];
        float4 ptB = *(const float4*)&Plds[(t0 + 64 + lane) * 4];
        float4 aA  = make_float4(ptA.x, -ptA.y, -ptA.z, -ptA.w);
        float4 aB  = make_float4(ptB.x, -ptB.y, -ptB.z, -ptB.w);

        const float NEGBIG = -3.402823466e38f;
        float A0 = NEGBIG, A1 = NEGBIG, A2 = NEGBIG, A3 = NEGBIG;
        float A4 = NEGBIG, A5 = NEGBIG, A6 = NEGBIG, A7 = NEGBIG;
        float B0 = NEGBIG, B1 = NEGBIG, B2 = NEGBIG, B3 = NEGBIG;
        float B4 = NEGBIG, B5 = NEGBIG, B6 = NEGBIG, B7 = NEGBIG;

        // ---- pass 1: chunk-local top-8 for both tokens ----
        for (int s = sBeg; s < sEnd; ++s) {
            float4 ps = *(const float4*)&Plds[s * 4];   // one read, two dots
            float dA = dot4(aA, ps);
            float dB = dot4(aB, ps);
            // wave-skip: INS8 is an exact no-op when d < v7
            if (__ballot((dA > A7) || (dB > B7))) {
                INS8(A0, A1, A2, A3, A4, A5, A6, A7, dA);
                INS8(B0, B1, B2, B3, B4, B5, B6, B7, dB);
            }
        }
        VT(w, 0, lane) = A0; VT(w, 1, lane) = A1;
        VT(w, 2, lane) = A2; VT(w, 3, lane) = A3;
        VT(w, 4, lane) = A4; VT(w, 5, lane) = A5;
        VT(w, 6, lane) = A6; VT(w, 7, lane) = A7;
        VT(w, 0, 64 + lane) = B0; VT(w, 1, 64 + lane) = B1;
        VT(w, 2, 64 + lane) = B2; VT(w, 3, 64 + lane) = B3;
        VT(w, 4, 64 + lane) = B4; VT(w, 5, 64 + lane) = B5;
        VT(w, 6, 64 + lane) = B6; VT(w, 7, 64 + lane) = B7;
        __syncthreads();                               // B2

        // ---- merge 16x8 candidates per token (redundant per wave) ----
        float mA0 = NEGBIG, mA1 = NEGBIG, mA2 = NEGBIG, mA3 = NEGBIG;
        float mA4 = NEGBIG, mA5 = NEGBIG, mA6 = NEGBIG, mA7 = NEGBIG;
        float mB0 = NEGBIG, mB1 = NEGBIG, mB2 = NEGBIG, mB3 = NEGBIG;
        float mB4 = NEGBIG, mB5 = NEGBIG, mB6 = NEGBIG, mB7 = NEGBIG;
#pragma unroll
        for (int w2 = 0; w2 < 16; ++w2) {
#pragma unroll
            for (int j = 0; j < 8; ++j) {
                float dA = VT(w2, j, lane);
                float dB = VT(w2, j, 64 + lane);
                INS8(mA0, mA1, mA2, mA3, mA4, mA5, mA6, mA7, dA);
                INS8(mB0, mB1, mB2, mB3, mB4, mB5, mB6, mB7, dB);
            }
        }
        const float th2A = mA1, th4A = mA3, th8A = mA7;
        const float th2B = mB1, th4B = mB3, th8B = mB7;
        __syncthreads();                               // B3 (vtop dead)

        // ---- pass 2: exact-membership partial sums, both tokens ----
        float a2x = 0.f, a2y = 0.f, a2z = 0.f, a2w = 0.f;
        float a4x = 0.f, a4y = 0.f, a4z = 0.f, a4w = 0.f;
        float a8x = 0.f, a8y = 0.f, a8z = 0.f, a8w = 0.f;
        float c2x = 0.f, c2y = 0.f, c2z = 0.f, c2w = 0.f;
        float c4x = 0.f, c4y = 0.f, c4z = 0.f, c4w = 0.f;
        float c8x = 0.f, c8y = 0.f, c8z = 0.f, c8w = 0.f;
        for (int s = sBeg; s < sEnd; ++s) {
            float4 ps = *(const float4*)&Plds[s * 4];
            float dA = dot4(aA, ps);
            float dB = dot4(aB, ps);
            if (dA >= th8A) {
                a8x += ps.x; a8y += ps.y; a8z += ps.z; a8w += ps.w;
                if (dA >= th4A) {
                    a4x += ps.x; a4y += ps.y; a4z += ps.z; a4w += ps.w;
                    if (dA >= th2A) {
                        a2x += ps.x; a2y += ps.y; a2z += ps.z; a2w += ps.w;
                    }
                }
            }
            if (dB >= th8B) {
                c8x += ps.x; c8y += ps.y; c8z += ps.z; c8w += ps.w;
                if (dB >= th4B) {
                    c4x += ps.x; c4y += ps.y; c4z += ps.z; c4w += ps.w;
                    if (dB >= th2B) {
                        c2x += ps.x; c2y += ps.y; c2z += ps.z; c2w += ps.w;
                    }
                }
            }
        }

        // ---- psum two-stage reduction in [8][12][128] ----
        if (w >= 8) {
            const int ws = w - 8;
            PS(ws, 0, lane) = a2x;  PS(ws, 1, lane) = a2y;
            PS(ws, 2, lane) = a2z;  PS(ws, 3, lane) = a2w;
            PS(ws, 4, lane) = a4x;  PS(ws, 5, lane) = a4y;
            PS(ws, 6, lane) = a4z;  PS(ws, 7, lane) = a4w;
            PS(ws, 8, lane) = a8x;  PS(ws, 9, lane) = a8y;
            PS(ws, 10, lane) = a8z; PS(ws, 11, lane) = a8w;
            PS(ws, 0, 64 + lane) = c2x;  PS(ws, 1, 64 + lane) = c2y;
            PS(ws, 2, 64 + lane) = c2z;  PS(ws, 3, 64 + lane) = c2w;
            PS(ws, 4, 64 + lane) = c4x;  PS(ws, 5, 64 + lane) = c4y;
            PS(ws, 6, 64 + lane) = c4z;  PS(ws, 7, 64 + lane) = c4w;
            PS(ws, 8, 64 + lane) = c8x;  PS(ws, 9, 64 + lane) = c8y;
            PS(ws, 10, 64 + lane) = c8z; PS(ws, 11, 64 + lane) = c8w;
        }
        __syncthreads();                               // B4a
        if (w < 8) {
            PS(w, 0, lane) += a2x;  PS(w, 1, lane) += a2y;
            PS(w, 2, lane) += a2z;  PS(w, 3, lane) += a2w;
            PS(w, 4, lane) += a4x;  PS(w, 5, lane) += a4y;
            PS(w, 6, lane) += a4z;  PS(w, 7, lane) += a4w;
            PS(w, 8, lane) += a8x;  PS(w, 9, lane) += a8y;
            PS(w, 10, lane) += a8z; PS(w, 11, lane) += a8w;
            PS(w, 0, 64 + lane) += c2x;  PS(w, 1, 64 + lane) += c2y;
            PS(w, 2, 64 + lane) += c2z;  PS(w, 3, 64 + lane) += c2w;
            PS(w, 4, 64 + lane) += c4x;  PS(w, 5, 64 + lane) += c4y;
            PS(w, 6, 64 + lane) += c4z;  PS(w, 7, 64 + lane) += c4w;
            PS(w, 8, 64 + lane) += c8x;  PS(w, 9, 64 + lane) += c8y;
            PS(w, 10, 64 + lane) += c8z; PS(w, 11, 64 + lane) += c8w;
        }
        __syncthreads();                               // B4b

        // ---- waves 0,1: reduce 8 slots + masses ----
        if (w < 2) {
            const int tl = w * 64 + lane;
            float tot[12];
#pragma unroll
            for (int c = 0; c < 12; ++c) {
                float acc = 0.f;
#pragma unroll
                for (int w2 = 0; w2 < 8; ++w2) acc += PS(w2, c, tl);
                tot[c] = acc;
            }
            const bool maskt = (t0 + tl) < L;
            const float MZ = sqrtf(1e-8f);
            auto massf = [&](float sx, float sy, float sz, float sw) -> float {
                float q = sx * sx;
                q = __builtin_fmaf(-sy, sy, q);
                q = __builtin_fmaf(-sz, sz, q);
                q = __builtin_fmaf(-sw, sw, q);
                q = fmaxf(q, 0.f);
                return sqrtf(q + 1e-8f);
            };
            mass_s[0][tl] = maskt ? massf(tot[0], tot[1], tot[2], tot[3]) : MZ;
            mass_s[1][tl] = maskt ? massf(tot[4], tot[5], tot[6], tot[7]) : MZ;
            mass_s[2][tl] = maskt ? massf(tot[8], tot[9], tot[10], tot[11]) : MZ;
        }
    } else {
        if (tid < 128) {
            const float MZ = sqrtf(1e-8f);
            mass_s[0][tid] = MZ;
            mass_s[1][tid] = MZ;
            mass_s[2][tid] = MZ;
        }
    }
    __syncthreads();                                   // B5 (common)

    // ---- h = gelu(mass @ W1 + b1), bf16 -> LDS (all 128 tokens) ----
    {
        const int tt = tid & 127;
        const int hr = tid >> 7;           // 0..7, wave-uniform (= w>>1)
        float q0 = mass_s[0][tt];
        float q1 = mass_s[1][tt];
        float q2 = mass_s[2][tt];
        unsigned short hv[8];
#pragma unroll
        for (int j = 0; j < 8; ++j) {
            int hh = hr * 8 + j;
            float pre = b1[hh];
            pre = __builtin_fmaf(q0, W1[hh], pre);
            pre = __builtin_fmaf(q1, W1[NH + hh], pre);
            pre = __builtin_fmaf(q2, W1[2 * NH + hh], pre);
            float g = 0.5f * pre * (1.0f + erff(pre * 0.70710678118654752f));
            hv[j] = f2bf(g);
        }
        *(short8*)&hs[tt][hr * 8] = *(const short8*)hv;
    }
    __syncthreads();                                   // B6

    // ---- MFMA: out[b*NT+t0 .. +127][0..511] = h @ W2 + b2 ----
    // wave w: m-slice (w>>2)*32 (32 tokens), n-slice (w&3)*128.
    const int col    = lane & 15;
    const int quad   = lane >> 4;
    const int mslice = w >> 2;             // 0..3
    const int nBase  = (w & 3) * 128;

    short8 afrag[2][2];
#pragma unroll
    for (int mt = 0; mt < 2; ++mt)
#pragma unroll
        for (int ks = 0; ks < 2; ++ks)
            afrag[mt][ks] = *(const short8*)&hs[mslice * 32 + mt * 16 + col][ks * 32 + quad * 8];

    float4v acc[2][8];
#pragma unroll
    for (int mt = 0; mt < 2; ++mt)
#pragma unroll
        for (int nt = 0; nt < 8; ++nt)
            acc[mt][nt] = (float4v)(0.f);

#pragma unroll
    for (int nt = 0; nt < 8; ++nt) {
        const unsigned short* wp = W2t + (nBase + nt * 16 + col) * NH + quad * 8;
        short8 bf0 = *(const short8*)(wp);
        short8 bf1 = *(const short8*)(wp + 32);
        acc[0][nt] = __builtin_amdgcn_mfma_f32_16x16x32_bf16(afrag[0][0], bf0, acc[0][nt], 0, 0, 0);
        acc[1][nt] = __builtin_amdgcn_mfma_f32_16x16x32_bf16(afrag[1][0], bf0, acc[1][nt], 0, 0, 0);
        acc[0][nt] = __builtin_amdgcn_mfma_f32_16x16x32_bf16(afrag[0][1], bf1, acc[0][nt], 0, 0, 0);
        acc[1][nt] = __builtin_amdgcn_mfma_f32_16x16x32_bf16(afrag[1][1], bf1, acc[1][nt], 0, 0, 0);
    }

#pragma unroll
    for (int nt = 0; nt < 8; ++nt) {
        float bias = b2[nBase + nt * 16 + col];
#pragma unroll
        for (int mt = 0; mt < 2; ++mt) {
            int mRow = b * NT + t0 + mslice * 32 + mt * 16 + quad * 4;
            size_t base = (size_t)mRow * ND + nBase + nt * 16 + col;
#pragma unroll
            for (int r = 0; r < 4; ++r) {
                out[base + (size_t)r * ND] = acc[mt][nt][r] + bias;
            }
        }
    }
}

extern "C" void kernel_launch(void* const* d_in, const int* in_sizes, int n_in,
                              void* d_out, int out_size, void* d_ws, size_t ws_size,
                              hipStream_t stream) {
    const float* tok  = (const float*)d_in[0];
    const int*   mask = (const int*)d_in[1];   // layout auto-detected in-kernel
    const float* W1   = (const float*)d_in[2];
    const float* b1   = (const float*)d_in[3];
    const float* W2   = (const float*)d_in[4];
    const float* b2   = (const float*)d_in[5];
    float*       out  = (float*)d_out;

    unsigned short* W2t = (unsigned short*)d_ws;       // 64 KB

    w2t_kernel<<<dim3(ND * NH / 256), dim3(256), 0, stream>>>(W2, W2t);

    dim3 gB(NT / 128, NB);
    fused_topk_mass_mlp_kernel<<<gB, dim3(1024), 0, stream>>>(
        tok, mask, W1, b1, W2t, b2, out);
}

// Round 11
// 157.619 us; speedup vs baseline: 1.2142x; 1.2142x over previous
//
#include <hip/hip_runtime.h>
#include <hip/hip_bf16.h>
#include <math.h>

#define NB 16
#define NT 2048
#define ND 512
#define NH 64

typedef __attribute__((ext_vector_type(8))) short short8;
typedef __attribute__((ext_vector_type(4))) float float4v;

__device__ __forceinline__ bool mask_is_bytes(const int* m) {
    return m[0] == 0x01010101;
}
__device__ __forceinline__ bool mask_at(const int* m, bool bytes, int i) {
    if (bytes) return ((const unsigned char*)m)[i] != 0;
    return m[i] != 0;
}

__device__ __forceinline__ float dot4(float4 a, float4 p) {
    float d = a.x * p.x;
    d = __builtin_fmaf(a.y, p.y, d);
    d = __builtin_fmaf(a.z, p.z, d);
    d = __builtin_fmaf(a.w, p.w, d);
    return d;
}

__device__ __forceinline__ unsigned short f2bf(float x) {
    unsigned int u = __float_as_uint(x);
    u += 0x7fffu + ((u >> 16) & 1u);
    return (unsigned short)(u >> 16);
}

// Sorted-descending top-8 insert of (D, SI): med3 value chain + exactly
// mirrored cndmask index chain. For insertion rank r (smallest j with D>v_j):
// values shift at r (med3 identity), indices: j<r keep, j==r take SI, j>r
// take idx_{j-1}. Ties (D == v_j) follow strict '>' in both chains.
#define INSVI(V0,V1,V2,V3,V4,V5,V6,V7,I0,I1,I2,I3,I4,I5,I6,I7,D,SI)  \
    {                                                                \
        bool c0 = (D) > V0, c1 = (D) > V1, c2 = (D) > V2,            \
             c3 = (D) > V3, c4 = (D) > V4, c5 = (D) > V5,            \
             c6 = (D) > V6, c7 = (D) > V7;                           \
        float n0 = fmaxf(V0, (D));                                   \
        float n1 = __builtin_amdgcn_fmed3f((D), V0, V1);             \
        float n2 = __builtin_amdgcn_fmed3f((D), V1, V2);             \
        float n3 = __builtin_amdgcn_fmed3f((D), V2, V3);             \
        float n4 = __builtin_amdgcn_fmed3f((D), V3, V4);             \
        float n5 = __builtin_amdgcn_fmed3f((D), V4, V5);             \
        float n6 = __builtin_amdgcn_fmed3f((D), V5, V6);             \
        float n7 = __builtin_amdgcn_fmed3f((D), V6, V7);             \
        int j0 = c0 ? (SI) : I0;                                     \
        int j1 = c0 ? I0 : (c1 ? (SI) : I1);                         \
        int j2 = c1 ? I1 : (c2 ? (SI) : I2);                         \
        int j3 = c2 ? I2 : (c3 ? (SI) : I3);                         \
        int j4 = c3 ? I3 : (c4 ? (SI) : I4);                         \
        int j5 = c4 ? I4 : (c5 ? (SI) : I5);                         \
        int j6 = c5 ? I5 : (c6 ? (SI) : I6);                         \
        int j7 = c6 ? I6 : (c7 ? (SI) : I7);                         \
        V0 = n0; V1 = n1; V2 = n2; V3 = n3;                          \
        V4 = n4; V5 = n5; V6 = n6; V7 = n7;                          \
        I0 = j0; I1 = j1; I2 = j2; I3 = j3;                          \
        I4 = j4; I5 = j5; I6 = j6; I7 = j7;                          \
    }

// ---------------------------------------------------------------------------
// Kernel A: one-time W2 fp32[k][n] -> bf16 W2t[n][k].
// ---------------------------------------------------------------------------
__global__ void __launch_bounds__(256) w2t_kernel(
        const float* __restrict__ W2, unsigned short* __restrict__ W2t) {
    int i = blockIdx.x * 256 + threadIdx.x;
    int n = i & (ND - 1), k = i >> 9;
    W2t[n * NH + k] = f2bf(W2[k * ND + n]);
}

// ---------------------------------------------------------------------------
// Kernel B: fused, ONE-PASS top-8 with index tracking (R8 shape: 512 thr,
// 8 waves, 64 tokens/block, grid 512 = 2 blocks/CU, 16 waves/CU).
//  1) stage P into LDS; L via ballot
//  2) single pass: per-wave top-8 (value,index) over its L/8 chunk
//  3) wave 0: flat-merge 8x8 candidates -> top-8 indices -> gather 8 P's
//     from LDS -> cumsum (sorted-desc order = reference order) -> masses
//  4) gelu + MFMA epilogue (verbatim R8, b*NT fix included)
// No pass 2, no psum scratch: LDS ~76 KB, 2 barriers fewer than R8.
// ---------------------------------------------------------------------------
__global__ void __launch_bounds__(512) fused_topk_mass_mlp_kernel(
        const float* __restrict__ tok,
        const int* __restrict__ mask,
        const float* __restrict__ W1,
        const float* __restrict__ b1,
        const unsigned short* __restrict__ W2t,
        const float* __restrict__ b2,
        float* __restrict__ out) {
    __shared__ float Plds[NT * 4];            // 32 KB
    __shared__ float vtV[8][8][64];           // 16 KB  top-8 values
    __shared__ int   vtI[8][8][64];           // 16 KB  top-8 indices
    __shared__ unsigned short hs[64][88];     // 11 KB
    __shared__ float mass_s[3][64];           // 768 B
    __shared__ int wcnt[8];

    const int b    = blockIdx.y;
    const int t0   = blockIdx.x * 64;
    const int tid  = threadIdx.x;
    const int lane = tid & 63;
    const int w    = tid >> 6;
    const bool mb  = mask_is_bytes(mask);

    const bool blockValid = mask_at(mask, mb, b * NT + t0);   // mask monotone

    if (blockValid) {
        // ---- stage tokens -> P in LDS; count L ----
        int cnt = 0;
#pragma unroll
        for (int it = 0; it < 4; ++it) {
            int i = tid + it * 512;
            float4 tv = ((const float4*)tok)[b * NT + i];
            bool m = mask_at(mask, mb, b * NT + i);
            float E = tv.x, Pt = tv.y, eta = tv.z, phi = tv.w;
            float px = Pt * cosf(phi);
            float py = Pt * sinf(phi);
            float pz = Pt * sinhf(fminf(fmaxf(eta, -20.f), 20.f));
            float4 pv = m ? make_float4(E, px, py, pz)
                          : make_float4(-1e30f, 0.f, 0.f, 0.f);
            *(float4*)&Plds[i * 4] = pv;
            cnt += (int)__popcll(__ballot(m));
        }
        if (lane == 0) wcnt[w] = cnt;
        __syncthreads();                               // B1

        int L = 0;
#pragma unroll
        for (int j = 0; j < 8; ++j) L += wcnt[j];
        const int C    = (L + 7) >> 3;
        const int sBeg = w * C;
        const int sEnd = min(sBeg + C, L);             // chunk len >= 121 > 8

        float4 pt = *(const float4*)&Plds[(t0 + lane) * 4];
        float4 a  = make_float4(pt.x, -pt.y, -pt.z, -pt.w);

        const float NEGBIG = -3.402823466e38f;
        float v0 = NEGBIG, v1 = NEGBIG, v2 = NEGBIG, v3 = NEGBIG;
        float v4 = NEGBIG, v5 = NEGBIG, v6 = NEGBIG, v7 = NEGBIG;
        int   i0 = 0, i1 = 0, i2 = 0, i3 = 0, i4 = 0, i5 = 0, i6 = 0, i7 = 0;

        // ---- single pass: chunk-local top-8 (value, index) ----
#pragma unroll 2
        for (int s = sBeg; s < sEnd; ++s) {
            float4 ps = *(const float4*)&Plds[s * 4];   // broadcast read
            float d = dot4(a, ps);
            INSVI(v0, v1, v2, v3, v4, v5, v6, v7,
                  i0, i1, i2, i3, i4, i5, i6, i7, d, s);
        }
        vtV[w][0][lane] = v0; vtI[w][0][lane] = i0;
        vtV[w][1][lane] = v1; vtI[w][1][lane] = i1;
        vtV[w][2][lane] = v2; vtI[w][2][lane] = i2;
        vtV[w][3][lane] = v3; vtI[w][3][lane] = i3;
        vtV[w][4][lane] = v4; vtI[w][4][lane] = i4;
        vtV[w][5][lane] = v5; vtI[w][5][lane] = i5;
        vtV[w][6][lane] = v6; vtI[w][6][lane] = i6;
        vtV[w][7][lane] = v7; vtI[w][7][lane] = i7;
        __syncthreads();                               // B2

        // ---- wave 0: flat merge of the other 7 waves' candidates ----
        if (w == 0) {
            for (int w2 = 1; w2 < 8; ++w2) {
#pragma unroll
                for (int j = 0; j < 8; ++j) {
                    float dv = vtV[w2][j][lane];        // lane-contiguous
                    int   di = vtI[w2][j][lane];
                    INSVI(v0, v1, v2, v3, v4, v5, v6, v7,
                          i0, i1, i2, i3, i4, i5, i6, i7, dv, di);
                }
            }
            // ---- gather top-8 P's, cumsum (desc order = ref order) ----
            float sx = 0.f, sy = 0.f, sz = 0.f, sw = 0.f;
            const bool maskt = (t0 + lane) < L;
            const float MZ = sqrtf(1e-8f);
            auto massf = [&](float gx, float gy, float gz, float gw) -> float {
                float q = gx * gx;
                q = __builtin_fmaf(-gy, gy, q);
                q = __builtin_fmaf(-gz, gz, q);
                q = __builtin_fmaf(-gw, gw, q);
                q = fmaxf(q, 0.f);
                return sqrtf(q + 1e-8f);
            };
            int idxs[8] = { i0, i1, i2, i3, i4, i5, i6, i7 };
#pragma unroll
            for (int j = 0; j < 8; ++j) {
                float4 pv = *(const float4*)&Plds[idxs[j] * 4];
                sx += pv.x; sy += pv.y; sz += pv.z; sw += pv.w;
                if (j == 1) mass_s[0][lane] = maskt ? massf(sx, sy, sz, sw) : MZ;
                if (j == 3) mass_s[1][lane] = maskt ? massf(sx, sy, sz, sw) : MZ;
                if (j == 7) mass_s[2][lane] = maskt ? massf(sx, sy, sz, sw) : MZ;
            }
        }
    } else {
        if (tid < 64) {
            const float MZ = sqrtf(1e-8f);
            mass_s[0][tid] = MZ;
            mass_s[1][tid] = MZ;
            mass_s[2][tid] = MZ;
        }
    }
    __syncthreads();                                   // B3 (common)

    // ---- h = gelu(mass @ W1 + b1), bf16 -> LDS ----
    {
        const int tt = lane;
        const int hr = w;                  // wave-uniform -> W1/b1 scalar loads
        float q0 = mass_s[0][tt];
        float q1 = mass_s[1][tt];
        float q2 = mass_s[2][tt];
        unsigned short hv[8];
#pragma unroll
        for (int j = 0; j < 8; ++j) {
            int hh = hr * 8 + j;
            float pre = b1[hh];
            pre = __builtin_fmaf(q0, W1[hh], pre);
            pre = __builtin_fmaf(q1, W1[NH + hh], pre);
            pre = __builtin_fmaf(q2, W1[2 * NH + hh], pre);
            float g = 0.5f * pre * (1.0f + erff(pre * 0.70710678118654752f));
            hv[j] = f2bf(g);
        }
        *(short8*)&hs[tt][hr * 8] = *(const short8*)hv;
    }
    __syncthreads();                                   // B4

    // ---- MFMA: out[b*NT + t0 .. +63][0..511] = h @ W2 + b2 ----
    const int col   = lane & 15;
    const int quad  = lane >> 4;
    const int mhalf = w >> 2;              // token half (0..1)
    const int nBase = (w & 3) * 128;

    short8 afrag[2][2];
#pragma unroll
    for (int mt = 0; mt < 2; ++mt)
#pragma unroll
        for (int ks = 0; ks < 2; ++ks)
            afrag[mt][ks] = *(const short8*)&hs[mhalf * 32 + mt * 16 + col][ks * 32 + quad * 8];

    float4v acc[2][8];
#pragma unroll
    for (int mt = 0; mt < 2; ++mt)
#pragma unroll
        for (int nt = 0; nt < 8; ++nt)
            acc[mt][nt] = (float4v)(0.f);

#pragma unroll
    for (int nt = 0; nt < 8; ++nt) {
        const unsigned short* wp = W2t + (nBase + nt * 16 + col) * NH + quad * 8;
        short8 bf0 = *(const short8*)(wp);
        short8 bf1 = *(const short8*)(wp + 32);
        acc[0][nt] = __builtin_amdgcn_mfma_f32_16x16x32_bf16(afrag[0][0], bf0, acc[0][nt], 0, 0, 0);
        acc[1][nt] = __builtin_amdgcn_mfma_f32_16x16x32_bf16(afrag[1][0], bf0, acc[1][nt], 0, 0, 0);
        acc[0][nt] = __builtin_amdgcn_mfma_f32_16x16x32_bf16(afrag[0][1], bf1, acc[0][nt], 0, 0, 0);
        acc[1][nt] = __builtin_amdgcn_mfma_f32_16x16x32_bf16(afrag[1][1], bf1, acc[1][nt], 0, 0, 0);
    }

#pragma unroll
    for (int nt = 0; nt < 8; ++nt) {
        float bias = b2[nBase + nt * 16 + col];
#pragma unroll
        for (int mt = 0; mt < 2; ++mt) {
            int mRow = b * NT + t0 + mhalf * 32 + mt * 16 + quad * 4;
            size_t base = (size_t)mRow * ND + nBase + nt * 16 + col;
#pragma unroll
            for (int r = 0; r < 4; ++r) {
                out[base + (size_t)r * ND] = acc[mt][nt][r] + bias;
            }
        }
    }
}

extern "C" void kernel_launch(void* const* d_in, const int* in_sizes, int n_in,
                              void* d_out, int out_size, void* d_ws, size_t ws_size,
                              hipStream_t stream) {
    const float* tok  = (const float*)d_in[0];
    const int*   mask = (const int*)d_in[1];   // layout auto-detected in-kernel
    const float* W1   = (const float*)d_in[2];
    const float* b1   = (const float*)d_in[3];
    const float* W2   = (const float*)d_in[4];
    const float* b2   = (const float*)d_in[5];
    float*       out  = (float*)d_out;

    unsigned short* W2t = (unsigned short*)d_ws;       // 64 KB

    w2t_kernel<<<dim3(ND * NH / 256), dim3(256), 0, stream>>>(W2, W2t);

    dim3 gB(NT / 64, NB);
    fused_topk_mass_mlp_kernel<<<gB, dim3(512), 0, stream>>>(
        tok, mask, W1, b1, W2t, b2, out);
}